// Round 1
// baseline (962.585 us; speedup 1.0000x reference)
//
#include <hip/hip_runtime.h>
#include <hip/hip_bf16.h>
#include <stdint.h>

#define BB 32
#define LL 1024
#define DD 1024
#define HH 16
#define DVV 64

typedef __bf16 bf16x8 __attribute__((ext_vector_type(8)));
typedef float floatx4 __attribute__((ext_vector_type(4)));

__device__ __forceinline__ unsigned short f2bf(float f) {
  union { float f; uint32_t u; } v; v.f = f;
  uint32_t u = v.u;
  uint32_t r = (u + 0x7fffu + ((u >> 16) & 1u)) >> 16;
  return (unsigned short)r;
}

// ---------- cast x (fp32 -> bf16), 1 float4 per thread ----------
__global__ void k_cast_x(const float* __restrict__ x, unsigned short* __restrict__ xbf) {
  int idx = blockIdx.x * 256 + threadIdx.x;
  float4 v = ((const float4*)x)[idx];
  ushort4 o;
  o.x = f2bf(v.x); o.y = f2bf(v.y); o.z = f2bf(v.z); o.w = f2bf(v.w);
  ((ushort4*)xbf)[idx] = o;
}

// ---------- transpose+cast wv [K,N] -> wvT [N,K] bf16 ----------
__global__ void k_trans_wv(const float* __restrict__ wv, unsigned short* __restrict__ wvT) {
  __shared__ unsigned short tile[64][72];
  int k0 = blockIdx.x * 64;
  int n0 = blockIdx.y * 64;
  int t = threadIdx.x;
  for (int i = 0; i < 4; ++i) {
    int idx = i * 256 + t;          // 0..1023
    int k = idx >> 4;               // row in tile
    int f = idx & 15;               // float4 index
    float4 v = ((const float4*)(wv + (size_t)(k0 + k) * DD + n0))[f];
    tile[f * 4 + 0][k] = f2bf(v.x);
    tile[f * 4 + 1][k] = f2bf(v.y);
    tile[f * 4 + 2][k] = f2bf(v.z);
    tile[f * 4 + 3][k] = f2bf(v.w);
  }
  __syncthreads();
  for (int i = 0; i < 8; ++i) {
    int idx = i * 256 + t;          // uint index 0..2047
    int n = idx >> 5;
    int c = idx & 31;
    uint32_t lo = tile[n][c * 2];
    uint32_t hi = tile[n][c * 2 + 1];
    ((uint32_t*)(wvT + (size_t)(n0 + n) * DD + k0))[c] = lo | (hi << 16);
  }
}

// ---------- q[b,n] = x[b,L-1,:] @ wq + bq ----------
__global__ void k_qproj(const float* __restrict__ x, const float* __restrict__ wq,
                        const float* __restrict__ bq, float* __restrict__ q) {
  int b = blockIdx.x;
  int n = blockIdx.y * 256 + threadIdx.x;
  const float* xl = x + ((size_t)b * LL + (LL - 1)) * DD;
  float acc = bq[n];
#pragma unroll 4
  for (int d = 0; d < DD; ++d) acc += xl[d] * wq[(size_t)d * DD + n];
  q[b * DD + n] = acc;
}

// ---------- qb[b,h] = bk_h . q[b,h,:] ----------
__global__ void k_qb(const float* __restrict__ bk, const float* __restrict__ q,
                     float* __restrict__ qb) {
  int b = blockIdx.x;
  int t = threadIdx.x;
  if (t < HH) {
    float acc = 0.f;
    for (int j = 0; j < DVV; ++j) acc += bk[t * DVV + j] * q[b * DD + t * DVV + j];
    qb[b * HH + t] = acc;
  }
}

// ---------- u[b,h,d] = sum_j wk[d, h*64+j] * q[b, h*64+j] ----------
__global__ void k_u(const float* __restrict__ wk, const float* __restrict__ q,
                    float* __restrict__ u) {
  int b = blockIdx.x;
  int d0 = blockIdx.y * 256;
  int t = threadIdx.x;
  float4 q4 = ((const float4*)(q + (size_t)b * DD))[t];  // elems 4t..4t+3
  int h = t >> 4;
  for (int r = 0; r < 256; ++r) {
    int d = d0 + r;
    float4 w4 = ((const float4*)(wk + (size_t)d * DD))[t];
    float p = w4.x * q4.x + w4.y * q4.y + w4.z * q4.z + w4.w * q4.w;
    p += __shfl_down(p, 8);
    p += __shfl_down(p, 4);
    p += __shfl_down(p, 2);
    p += __shfl_down(p, 1);
    if ((t & 15) == 0) u[((size_t)(b * HH + h)) * DD + d] = p;
  }
}

// ---------- s[b,h,l] = (x[b,l,:].u[b,h,:] + qb) * rate[l] / temp ----------
__global__ void k_s(const float* __restrict__ x, const float* __restrict__ u,
                    const float* __restrict__ qb, float* __restrict__ s) {
  int bb = blockIdx.x >> 6;
  int rc = blockIdx.x & 63;
  int t = threadIdx.x;
  int row = rc * 16 + (t >> 4);
  int h = t & 15;
  const float4* xr = (const float4*)(x + ((size_t)(bb * LL + row)) * DD);
  const float4* ur = (const float4*)(u + ((size_t)(bb * HH + h)) * DD);
  float acc = 0.f;
  for (int i = 0; i < DD / 4; ++i) {
    float4 a = xr[i];
    float4 c = ur[i];
    acc += a.x * c.x + a.y * c.y + a.z * c.z + a.w * c.w;
  }
  float rate = (float)(LL - row - 1) * (1.0f / LL) + 1.0f;
  float val = (acc + qb[bb * HH + h]) * rate * (1.0f / 32.00001f);
  s[((size_t)(bb * HH + h)) * LL + row] = val;
}

// ---------- log_softmax over l, then c[b,l,h] = (s - lse) * rate[l] ----------
__global__ void k_softmax(const float* __restrict__ s, float* __restrict__ c) {
  int bh = blockIdx.x;  // b*16 + h
  int t = threadIdx.x;
  __shared__ float red[8];
  float4 v = ((const float4*)(s + (size_t)bh * LL))[t];
  float m = fmaxf(fmaxf(v.x, v.y), fmaxf(v.z, v.w));
  for (int off = 32; off; off >>= 1) m = fmaxf(m, __shfl_down(m, off));
  if ((t & 63) == 0) red[t >> 6] = m;
  __syncthreads();
  m = fmaxf(fmaxf(red[0], red[1]), fmaxf(red[2], red[3]));
  float e = expf(v.x - m) + expf(v.y - m) + expf(v.z - m) + expf(v.w - m);
  for (int off = 32; off; off >>= 1) e += __shfl_down(e, off);
  if ((t & 63) == 0) red[4 + (t >> 6)] = e;
  __syncthreads();
  float lse = m + logf(red[4] + red[5] + red[6] + red[7]);
  int b = bh >> 4, h = bh & 15;
  float outv[4] = {v.x - lse, v.y - lse, v.z - lse, v.w - lse};
  for (int i = 0; i < 4; ++i) {
    int l = t * 4 + i;
    float rate = (float)(LL - l - 1) * (1.0f / LL) + 1.0f;
    c[((size_t)(b * LL + l)) * HH + h] = outv[i] * rate;
  }
}

// ---------- GEMM: out_pre = coef * (xbf @ wv + bv) + x  (pre-LN), m97-style ----------
__global__ __launch_bounds__(256)
void k_gemm(const unsigned short* __restrict__ A,   // xbf [32768][1024]
            const unsigned short* __restrict__ Bt,  // wvT [1024 n][1024 k]
            const float* __restrict__ coef,         // [32768][16]
            const float* __restrict__ bv,           // [1024]
            const float* __restrict__ xres,         // fp32 residual
            float* __restrict__ out) {
  __shared__ __align__(16) unsigned short lds[8192];  // As 128x32, Bs 128x32
  unsigned short* As = lds;
  unsigned short* Bs = lds + 4096;
  int t = threadIdx.x;
  int wave = t >> 6, lane = t & 63;
  int row0 = blockIdx.x * 128;
  int col0 = blockIdx.y * 128;
  int mw = (wave & 1) * 64;
  int nw = (wave >> 1) * 64;
  int lr = lane & 15, lq = lane >> 4;
  int lm = lane >> 2, lp = lane & 3;

  floatx4 zero = {0.f, 0.f, 0.f, 0.f};
  floatx4 acc[4][4];
#pragma unroll
  for (int i = 0; i < 4; ++i)
#pragma unroll
    for (int j = 0; j < 4; ++j) acc[i][j] = zero;

  for (int ks = 0; ks < 1024; ks += 32) {
    __syncthreads();  // previous iter's LDS reads done before overwrite
#pragma unroll
    for (int i = 0; i < 2; ++i) {
      int seg = i * 4 + wave;          // 0..7, wave-uniform
      int m = seg * 16 + lm;           // 0..127
      const unsigned short* gA = A + (size_t)(row0 + m) * 1024 + ks + lp * 8;
      __builtin_amdgcn_global_load_lds(
          (const __attribute__((address_space(1))) void*)gA,
          (__attribute__((address_space(3))) void*)(As + seg * 512), 16, 0, 0);
      const unsigned short* gB = Bt + (size_t)(col0 + m) * 1024 + ks + lp * 8;
      __builtin_amdgcn_global_load_lds(
          (const __attribute__((address_space(1))) void*)gB,
          (__attribute__((address_space(3))) void*)(Bs + seg * 512), 16, 0, 0);
    }
    __syncthreads();
    bf16x8 a[4], b[4];
#pragma unroll
    for (int i = 0; i < 4; ++i)
      a[i] = *(const bf16x8*)(As + (mw + i * 16 + lr) * 32 + lq * 8);
#pragma unroll
    for (int j = 0; j < 4; ++j)
      b[j] = *(const bf16x8*)(Bs + (nw + j * 16 + lr) * 32 + lq * 8);
#pragma unroll
    for (int i = 0; i < 4; ++i)
#pragma unroll
      for (int j = 0; j < 4; ++j)
        acc[i][j] = __builtin_amdgcn_mfma_f32_16x16x32_bf16(a[i], b[j], acc[i][j], 0, 0, 0);
  }

  // epilogue: coef[row, h] * (v + bv[col]) + xres -> out (pre-LN)
#pragma unroll
  for (int i = 0; i < 4; ++i) {
#pragma unroll
    for (int j = 0; j < 4; ++j) {
      int gcol = col0 + nw + j * 16 + lr;
      int h = gcol >> 6;
      float bvn = bv[gcol];
#pragma unroll
      for (int r = 0; r < 4; ++r) {
        int grow = row0 + mw + i * 16 + lq * 4 + r;
        float v = acc[i][j][r] + bvn;
        float cf = coef[(size_t)grow * 16 + h];
        out[(size_t)grow * 1024 + gcol] = cf * v + xres[(size_t)grow * 1024 + gcol];
      }
    }
  }
}

// ---------- in-place LayerNorm over last dim ----------
__global__ void k_ln(float* __restrict__ out, const float* __restrict__ gamma,
                     const float* __restrict__ beta) {
  int row = blockIdx.x;
  int t = threadIdx.x;
  __shared__ float red[8];
  float4 v = ((const float4*)(out + (size_t)row * DD))[t];
  float s = v.x + v.y + v.z + v.w;
  float sq = v.x * v.x + v.y * v.y + v.z * v.z + v.w * v.w;
  for (int off = 32; off; off >>= 1) {
    s += __shfl_down(s, off);
    sq += __shfl_down(sq, off);
  }
  int wave = t >> 6, lane = t & 63;
  if (lane == 0) { red[wave] = s; red[4 + wave] = sq; }
  __syncthreads();
  s = red[0] + red[1] + red[2] + red[3];
  sq = red[4] + red[5] + red[6] + red[7];
  float mean = s * (1.0f / DD);
  float var = sq * (1.0f / DD) - mean * mean;
  float rstd = rsqrtf(var + 1e-5f);
  float4 g = ((const float4*)gamma)[t];
  float4 bb = ((const float4*)beta)[t];
  float4 o;
  o.x = (v.x - mean) * rstd * g.x + bb.x;
  o.y = (v.y - mean) * rstd * g.y + bb.y;
  o.z = (v.z - mean) * rstd * g.z + bb.z;
  o.w = (v.w - mean) * rstd * g.w + bb.w;
  ((float4*)(out + (size_t)row * DD))[t] = o;
}

extern "C" void kernel_launch(void* const* d_in, const int* in_sizes, int n_in,
                              void* d_out, int out_size, void* d_ws, size_t ws_size,
                              hipStream_t stream) {
  (void)in_sizes; (void)n_in; (void)out_size; (void)ws_size;
  const float* x     = (const float*)d_in[0];
  const float* wq    = (const float*)d_in[1];
  const float* bq    = (const float*)d_in[2];
  const float* wk    = (const float*)d_in[3];
  const float* bk    = (const float*)d_in[4];
  const float* wv    = (const float*)d_in[5];
  const float* bv    = (const float*)d_in[6];
  const float* gamma = (const float*)d_in[7];
  const float* beta  = (const float*)d_in[8];
  float* out = (float*)d_out;
  char* ws = (char*)d_ws;

  unsigned short* xbf = (unsigned short*)(ws);                 // 67108864 B
  unsigned short* wvT = (unsigned short*)(ws + 67108864);      //  2097152 B
  float* qv  = (float*)(ws + 69206016);                        //   131072 B
  float* uv  = (float*)(ws + 69337088);                        //  2097152 B
  float* qbv = (float*)(ws + 71434240);                        //     2048 B (pad 4096)
  float* sv  = (float*)(ws + 71438336);                        //  2097152 B
  float* cv  = (float*)(ws + 73535488);                        //  2097152 B -> end 75.6 MB

  k_cast_x<<<32768, 256, 0, stream>>>(x, xbf);
  k_trans_wv<<<dim3(16, 16), 256, 0, stream>>>(wv, wvT);
  k_qproj<<<dim3(32, 4), 256, 0, stream>>>(x, wq, bq, qv);
  k_qb<<<32, 64, 0, stream>>>(bk, qv, qbv);
  k_u<<<dim3(32, 4), 256, 0, stream>>>(wk, qv, uv);
  k_s<<<2048, 256, 0, stream>>>(x, uv, qbv, sv);
  k_softmax<<<512, 256, 0, stream>>>(sv, cv);
  k_gemm<<<dim3(256, 8), 256, 0, stream>>>(xbf, wvT, cv, bv, x, out);
  k_ln<<<32768, 256, 0, stream>>>(out, gamma, beta);
}

// Round 2
// 620.017 us; speedup vs baseline: 1.5525x; 1.5525x over previous
//
#include <hip/hip_runtime.h>
#include <hip/hip_bf16.h>
#include <stdint.h>

#define BB 32
#define LL 1024
#define DD 1024
#define HH 16
#define DVV 64

typedef __bf16 bf16x8 __attribute__((ext_vector_type(8)));
typedef float floatx4 __attribute__((ext_vector_type(4)));

__device__ __forceinline__ unsigned short f2bf(float f) {
  union { float f; uint32_t u; } v; v.f = f;
  uint32_t u = v.u;
  uint32_t r = (u + 0x7fffu + ((u >> 16) & 1u)) >> 16;
  return (unsigned short)r;
}

// ---------- cast x (fp32 -> bf16), 1 float4 per thread ----------
__global__ void k_cast_x(const float* __restrict__ x, unsigned short* __restrict__ xbf) {
  int idx = blockIdx.x * 256 + threadIdx.x;
  float4 v = ((const float4*)x)[idx];
  ushort4 o;
  o.x = f2bf(v.x); o.y = f2bf(v.y); o.z = f2bf(v.z); o.w = f2bf(v.w);
  ((ushort4*)xbf)[idx] = o;
}

// ---------- transpose+cast wv [K,N] -> wvT [N,K] bf16 ----------
__global__ void k_trans_wv(const float* __restrict__ wv, unsigned short* __restrict__ wvT) {
  __shared__ unsigned short tile[64][72];
  int k0 = blockIdx.x * 64;
  int n0 = blockIdx.y * 64;
  int t = threadIdx.x;
  for (int i = 0; i < 4; ++i) {
    int idx = i * 256 + t;          // 0..1023
    int k = idx >> 4;               // row in tile
    int f = idx & 15;               // float4 index
    float4 v = ((const float4*)(wv + (size_t)(k0 + k) * DD + n0))[f];
    tile[f * 4 + 0][k] = f2bf(v.x);
    tile[f * 4 + 1][k] = f2bf(v.y);
    tile[f * 4 + 2][k] = f2bf(v.z);
    tile[f * 4 + 3][k] = f2bf(v.w);
  }
  __syncthreads();
  for (int i = 0; i < 8; ++i) {
    int idx = i * 256 + t;          // uint index 0..2047
    int n = idx >> 5;
    int c = idx & 31;
    uint32_t lo = tile[n][c * 2];
    uint32_t hi = tile[n][c * 2 + 1];
    ((uint32_t*)(wvT + (size_t)(n0 + n) * DD + k0))[c] = lo | (hi << 16);
  }
}

// ---------- q init: q[b,n] = bq[n] ----------
__global__ void k_qinit(const float* __restrict__ bq, float* __restrict__ q) {
  int t = blockIdx.x * 256 + threadIdx.x;
  q[t] = bq[t & (DD - 1)];
}

// ---------- q[b,n] += x[b,L-1,kp*256..] @ wq[kp*256.., n]  (K-split x4, atomic) ----------
__global__ void k_qproj(const float* __restrict__ x, const float* __restrict__ wq,
                        float* __restrict__ q) {
  int b = blockIdx.x;
  int kp = blockIdx.y;
  int n = blockIdx.z * 256 + threadIdx.x;
  const float* xl = x + ((size_t)b * LL + (LL - 1)) * DD + kp * 256;
  const float* w = wq + (size_t)kp * 256 * DD + n;
  float a0 = 0.f, a1 = 0.f, a2 = 0.f, a3 = 0.f;
#pragma unroll 4
  for (int d = 0; d < 256; d += 4) {
    a0 += xl[d + 0] * w[(size_t)(d + 0) * DD];
    a1 += xl[d + 1] * w[(size_t)(d + 1) * DD];
    a2 += xl[d + 2] * w[(size_t)(d + 2) * DD];
    a3 += xl[d + 3] * w[(size_t)(d + 3) * DD];
  }
  atomicAdd(&q[b * DD + n], (a0 + a1) + (a2 + a3));
}

// ---------- qb[b,h] = bk_h . q[b,h,:] ----------
__global__ void k_qb(const float* __restrict__ bk, const float* __restrict__ q,
                     float* __restrict__ qb) {
  int b = blockIdx.x;
  int t = threadIdx.x;
  if (t < HH) {
    float acc = 0.f;
    for (int j = 0; j < DVV; ++j) acc += bk[t * DVV + j] * q[b * DD + t * DVV + j];
    qb[b * HH + t] = acc;
  }
}

// ---------- u[b,h,d] = sum_j wk[d, h*64+j] * q[b, h*64+j] ----------
__global__ void k_u(const float* __restrict__ wk, const float* __restrict__ q,
                    float* __restrict__ u) {
  int b = blockIdx.x;
  int d0 = blockIdx.y * 256;
  int t = threadIdx.x;
  float4 q4 = ((const float4*)(q + (size_t)b * DD))[t];  // elems 4t..4t+3
  int h = t >> 4;
  for (int r = 0; r < 256; ++r) {
    int d = d0 + r;
    float4 w4 = ((const float4*)(wk + (size_t)d * DD))[t];
    float p = w4.x * q4.x + w4.y * q4.y + w4.z * q4.z + w4.w * q4.w;
    p += __shfl_down(p, 8);
    p += __shfl_down(p, 4);
    p += __shfl_down(p, 2);
    p += __shfl_down(p, 1);
    if ((t & 15) == 0) u[((size_t)(b * HH + h)) * DD + d] = p;
  }
}

// ---------- s[b,h,l]: coalesced, LDS-staged u, butterfly-distribute reduce ----------
// block: 4 waves x 4 rows = 16 rows; grid = 32 b x 64 row-chunks
__global__ __launch_bounds__(256)
void k_s(const float* __restrict__ x, const float* __restrict__ u,
         const float* __restrict__ qb, float* __restrict__ s) {
  __shared__ float uls[HH * DD];  // 64 KB
  int b = blockIdx.x >> 6;
  int rc = blockIdx.x & 63;
  int t = threadIdx.x;
  int wave = t >> 6, lane = t & 63;
  const float4* ug = (const float4*)(u + (size_t)b * HH * DD);
#pragma unroll
  for (int i = 0; i < 16; ++i)
    ((float4*)uls)[i * 256 + t] = ug[i * 256 + t];
  __syncthreads();
  int row0 = rc * 16 + wave * 4;
  const float* xb = x + ((size_t)b * LL + row0) * DD;
  float p[64];
#pragma unroll
  for (int v = 0; v < 64; ++v) p[v] = 0.f;
#pragma unroll
  for (int i = 0; i < 4; ++i) {
    float4 xv[4];
#pragma unroll
    for (int r = 0; r < 4; ++r)
      xv[r] = ((const float4*)(xb + (size_t)r * DD))[i * 64 + lane];
#pragma unroll
    for (int h = 0; h < HH; ++h) {
      float4 uv = ((const float4*)(uls + h * DD))[i * 64 + lane];
#pragma unroll
      for (int r = 0; r < 4; ++r)
        p[h * 4 + r] += xv[r].x * uv.x + xv[r].y * uv.y + xv[r].z * uv.z + xv[r].w * uv.w;
    }
  }
  // butterfly-distribute: after 6 levels, lane L holds full sum of index L
#pragma unroll
  for (int k = 0; k < 6; ++k) {
    int bit = (lane >> k) & 1;
    int m = 32 >> k;
    float np[32];
#pragma unroll
    for (int j = 0; j < m; ++j) {
      float a = p[2 * j], c = p[2 * j + 1];
      float tosend = bit ? a : c;
      float recv = __shfl_xor(tosend, 1 << k);
      float keep = bit ? c : a;
      np[j] = keep + recv;
    }
#pragma unroll
    for (int j = 0; j < m; ++j) p[j] = np[j];
  }
  int h = lane >> 2, r = lane & 3;
  int row = row0 + r;
  float rate = (float)(LL - row - 1) * (1.0f / LL) + 1.0f;
  float val = (p[0] + qb[b * HH + h]) * rate * (1.0f / 32.00001f);
  s[((size_t)(b * HH + h)) * LL + row] = val;
}

// ---------- log_softmax over l, then c[b,l,h] = (s - lse) * rate[l] ----------
__global__ void k_softmax(const float* __restrict__ s, float* __restrict__ c) {
  int bh = blockIdx.x;  // b*16 + h
  int t = threadIdx.x;
  __shared__ float red[8];
  float4 v = ((const float4*)(s + (size_t)bh * LL))[t];
  float m = fmaxf(fmaxf(v.x, v.y), fmaxf(v.z, v.w));
  for (int off = 32; off; off >>= 1) m = fmaxf(m, __shfl_down(m, off));
  if ((t & 63) == 0) red[t >> 6] = m;
  __syncthreads();
  m = fmaxf(fmaxf(red[0], red[1]), fmaxf(red[2], red[3]));
  float e = expf(v.x - m) + expf(v.y - m) + expf(v.z - m) + expf(v.w - m);
  for (int off = 32; off; off >>= 1) e += __shfl_down(e, off);
  if ((t & 63) == 0) red[4 + (t >> 6)] = e;
  __syncthreads();
  float lse = m + logf(red[4] + red[5] + red[6] + red[7]);
  int b = bh >> 4, h = bh & 15;
  float outv[4] = {v.x - lse, v.y - lse, v.z - lse, v.w - lse};
  for (int i = 0; i < 4; ++i) {
    int l = t * 4 + i;
    float rate = (float)(LL - l - 1) * (1.0f / LL) + 1.0f;
    c[((size_t)(b * LL + l)) * HH + h] = outv[i] * rate;
  }
}

// ---------- GEMM: out_pre = coef * (xbf @ wv + bv) + x  (pre-LN), m97-style ----------
__global__ __launch_bounds__(256)
void k_gemm(const unsigned short* __restrict__ A,   // xbf [32768][1024]
            const unsigned short* __restrict__ Bt,  // wvT [1024 n][1024 k]
            const float* __restrict__ coef,         // [32768][16]
            const float* __restrict__ bv,           // [1024]
            const float* __restrict__ xres,         // fp32 residual
            float* __restrict__ out) {
  __shared__ __align__(16) unsigned short lds[8192];  // As 128x32, Bs 128x32
  unsigned short* As = lds;
  unsigned short* Bs = lds + 4096;
  int t = threadIdx.x;
  int wave = t >> 6, lane = t & 63;
  int row0 = blockIdx.x * 128;
  int col0 = blockIdx.y * 128;
  int mw = (wave & 1) * 64;
  int nw = (wave >> 1) * 64;
  int lr = lane & 15, lq = lane >> 4;
  int lm = lane >> 2, lp = lane & 3;

  floatx4 zero = {0.f, 0.f, 0.f, 0.f};
  floatx4 acc[4][4];
#pragma unroll
  for (int i = 0; i < 4; ++i)
#pragma unroll
    for (int j = 0; j < 4; ++j) acc[i][j] = zero;

  for (int ks = 0; ks < 1024; ks += 32) {
    __syncthreads();  // previous iter's LDS reads done before overwrite
#pragma unroll
    for (int i = 0; i < 2; ++i) {
      int seg = i * 4 + wave;          // 0..7, wave-uniform
      int m = seg * 16 + lm;           // 0..127
      const unsigned short* gA = A + (size_t)(row0 + m) * 1024 + ks + lp * 8;
      __builtin_amdgcn_global_load_lds(
          (const __attribute__((address_space(1))) void*)gA,
          (__attribute__((address_space(3))) void*)(As + seg * 512), 16, 0, 0);
      const unsigned short* gB = Bt + (size_t)(col0 + m) * 1024 + ks + lp * 8;
      __builtin_amdgcn_global_load_lds(
          (const __attribute__((address_space(1))) void*)gB,
          (__attribute__((address_space(3))) void*)(Bs + seg * 512), 16, 0, 0);
    }
    __syncthreads();
    bf16x8 a[4], b[4];
#pragma unroll
    for (int i = 0; i < 4; ++i)
      a[i] = *(const bf16x8*)(As + (mw + i * 16 + lr) * 32 + lq * 8);
#pragma unroll
    for (int j = 0; j < 4; ++j)
      b[j] = *(const bf16x8*)(Bs + (nw + j * 16 + lr) * 32 + lq * 8);
#pragma unroll
    for (int i = 0; i < 4; ++i)
#pragma unroll
      for (int j = 0; j < 4; ++j)
        acc[i][j] = __builtin_amdgcn_mfma_f32_16x16x32_bf16(a[i], b[j], acc[i][j], 0, 0, 0);
  }

  // epilogue: coef[row, h] * (v + bv[col]) + xres -> out (pre-LN)
#pragma unroll
  for (int i = 0; i < 4; ++i) {
#pragma unroll
    for (int j = 0; j < 4; ++j) {
      int gcol = col0 + nw + j * 16 + lr;
      int h = gcol >> 6;
      float bvn = bv[gcol];
#pragma unroll
      for (int r = 0; r < 4; ++r) {
        int grow = row0 + mw + i * 16 + lq * 4 + r;
        float v = acc[i][j][r] + bvn;
        float cf = coef[(size_t)grow * 16 + h];
        out[(size_t)grow * 1024 + gcol] = cf * v + xres[(size_t)grow * 1024 + gcol];
      }
    }
  }
}

// ---------- in-place LayerNorm over last dim ----------
__global__ void k_ln(float* __restrict__ out, const float* __restrict__ gamma,
                     const float* __restrict__ beta) {
  int row = blockIdx.x;
  int t = threadIdx.x;
  __shared__ float red[8];
  float4 v = ((const float4*)(out + (size_t)row * DD))[t];
  float s = v.x + v.y + v.z + v.w;
  float sq = v.x * v.x + v.y * v.y + v.z * v.z + v.w * v.w;
  for (int off = 32; off; off >>= 1) {
    s += __shfl_down(s, off);
    sq += __shfl_down(sq, off);
  }
  int wave = t >> 6, lane = t & 63;
  if (lane == 0) { red[wave] = s; red[4 + wave] = sq; }
  __syncthreads();
  s = red[0] + red[1] + red[2] + red[3];
  sq = red[4] + red[5] + red[6] + red[7];
  float mean = s * (1.0f / DD);
  float var = sq * (1.0f / DD) - mean * mean;
  float rstd = rsqrtf(var + 1e-5f);
  float4 g = ((const float4*)gamma)[t];
  float4 bb = ((const float4*)beta)[t];
  float4 o;
  o.x = (v.x - mean) * rstd * g.x + bb.x;
  o.y = (v.y - mean) * rstd * g.y + bb.y;
  o.z = (v.z - mean) * rstd * g.z + bb.z;
  o.w = (v.w - mean) * rstd * g.w + bb.w;
  ((float4*)(out + (size_t)row * DD))[t] = o;
}

extern "C" void kernel_launch(void* const* d_in, const int* in_sizes, int n_in,
                              void* d_out, int out_size, void* d_ws, size_t ws_size,
                              hipStream_t stream) {
  (void)in_sizes; (void)n_in; (void)out_size; (void)ws_size;
  const float* x     = (const float*)d_in[0];
  const float* wq    = (const float*)d_in[1];
  const float* bq    = (const float*)d_in[2];
  const float* wk    = (const float*)d_in[3];
  const float* bk    = (const float*)d_in[4];
  const float* wv    = (const float*)d_in[5];
  const float* bv    = (const float*)d_in[6];
  const float* gamma = (const float*)d_in[7];
  const float* beta  = (const float*)d_in[8];
  float* out = (float*)d_out;
  char* ws = (char*)d_ws;

  unsigned short* xbf = (unsigned short*)(ws);                 // 67108864 B
  unsigned short* wvT = (unsigned short*)(ws + 67108864);      //  2097152 B
  float* qv  = (float*)(ws + 69206016);                        //   131072 B
  float* uv  = (float*)(ws + 69337088);                        //  2097152 B
  float* qbv = (float*)(ws + 71434240);                        //     2048 B (pad 4096)
  float* sv  = (float*)(ws + 71438336);                        //  2097152 B
  float* cv  = (float*)(ws + 73535488);                        //  2097152 B -> end 75.6 MB

  k_cast_x<<<32768, 256, 0, stream>>>(x, xbf);
  k_trans_wv<<<dim3(16, 16), 256, 0, stream>>>(wv, wvT);
  k_qinit<<<128, 256, 0, stream>>>(bq, qv);
  k_qproj<<<dim3(32, 4, 4), 256, 0, stream>>>(x, wq, qv);
  k_qb<<<32, 64, 0, stream>>>(bk, qv, qbv);
  k_u<<<dim3(32, 4), 256, 0, stream>>>(wk, qv, uv);
  k_s<<<2048, 256, 0, stream>>>(x, uv, qbv, sv);
  k_softmax<<<512, 256, 0, stream>>>(sv, cv);
  k_gemm<<<dim3(256, 8), 256, 0, stream>>>(xbf, wvT, cv, bv, x, out);
  k_ln<<<32768, 256, 0, stream>>>(out, gamma, beta);
}